// Round 8
// baseline (83.361 us; speedup 1.0000x reference)
//
#include <hip/hip_runtime.h>
#include <math.h>

#define NITER 25

// fp64 rcp via v_rcp_f64 + 2 Newton refinements (~1 ulp).
__device__ __forceinline__ double fast_rcp(double x) {
#if __has_builtin(__builtin_amdgcn_rcp)
    double r = __builtin_amdgcn_rcp(x);
    r = fma(fma(-x, r, 1.0), r, r);
    r = fma(fma(-x, r, 1.0), r, r);
    return r;
#else
    return 1.0 / x;
#endif
}

// fp32 rcp for the fraction-to-boundary ratios only.
__device__ __forceinline__ float fast_rcpf(float x) {
#if __has_builtin(__builtin_amdgcn_rcpf)
    return __builtin_amdgcn_rcpf(x);
#else
    return 1.0f / x;
#endif
}

// Per-thread fp64 interior-point LCP, 25 iterations.
// Solve of the 4x4 Schur system
//   [[1+D0, 0,    0,    0 ],   [b0]
//    [0,    1+D1, -1,   1 ], = [b1]
//    [0,   -1,    1+D2, 1 ],   [b2]
//    [mu,  -1,   -1,    D3]]   [b3]
// via exact Cramer (row 0 has a single nonzero -> dl0 = b0/(1+D0); 3x3
// cofactors for the rest), with a per-lane conditioning check that falls
// back to the round-6 pivoted GE for degenerate lanes (lam crossing 0 ->
// 1+D0 or det3 ~ 0; pivoted GE stays finite there, Cramer NaNs).
// Wave-uniform early exit once every lane's step is < 1e-11 (sigma=0.1
// centering contracts muc ~10x/iter; skipped tail changes z by < 2.5e-10).
__global__ __launch_bounds__(256) void lcp_kernel(
    const float* __restrict__ pv, const float* __restrict__ mu_p,
    float* __restrict__ out, int n)
{
    int i = blockIdx.x * blockDim.x + threadIdx.x;
    if (i >= n) return;
    const double mu = (double)mu_p[0];
    const double SIG = 0.1;

    const float2 v = ((const float2*)pv)[i];
    const double q0 = -(double)v.x - 2.0;   // q = -v + (-2, 1), MASS=1
    const double q1 = -(double)v.y + 1.0;

    double z0 = -q0, z1 = -q1;
    double lam[4] = {1.0, 1.0, 1.0, 1.0};
    double s[4]   = {1.0, 1.0, 1.0, 1.0};

    for (int it = 0; it < NITER; ++it) {
        // residuals (same formulas as reference)
        double rd0 = z0 + q0 + (lam[1] - lam[2]);
        double rd1 = z1 + q1 - lam[0];
        double rp0 = -z1 + s[0];
        double rp1 =  z0 + s[1] - lam[3];
        double rp2 = -z0 + s[2] - lam[3];
        double rp3 =  s[3] - (mu * lam[0] - lam[1] - lam[2]);

        double sl0 = s[0]*lam[0], sl1 = s[1]*lam[1], sl2 = s[2]*lam[2], sl3 = s[3]*lam[3];
        double muc = 0.25 * (sl0 + sl1 + sl2 + sl3);

        double il0 = fast_rcp(lam[0]), il1 = fast_rcp(lam[1]);
        double il2 = fast_rcp(lam[2]), il3 = fast_rcp(lam[3]);
        double D0 = s[0]*il0, D1 = s[1]*il1, D2 = s[2]*il2, D3 = s[3]*il3;

        // Schur rhs: b = r_pri - r_cent/lam - G*r_dual
        double b0 = rp0 - (sl0 - SIG*muc)*il0 + rd1;
        double b1 = rp1 - (sl1 - SIG*muc)*il1 - rd0;
        double b2 = rp2 - (sl2 - SIG*muc)*il2 + rd0;
        double b3 = rp3 - (sl3 - SIG*muc)*il3;

        double a0 = 1.0 + D0, a1 = 1.0 + D1, a2 = 1.0 + D2, d3 = D3;

        // ---- Cramer fast path ----
        double CE1 = fma(a2, d3, 1.0);            // a2*d3 + 1
        double det3 = fma(a1, CE1, a2 - d3 + 2.0); // a1*a2*d3 + a1 + a2 - d3 + 2
        double Em1 = d3 - 1.0;
        double C1  = a2 + 1.0;

        double ia0 = fast_rcp(a0);
        double dl0 = b0 * ia0;
        double B3  = fma(-mu, dl0, b3);
        double idet3 = fast_rcp(det3);

        double dl1 = (b1*CE1 + b2*Em1 - B3*C1) * idet3;
        double dl2 = (a1*fma(b2, d3, -B3) + b1*Em1 + b2 - B3) * idet3;
        double dl3 = (a1*fma(a2, B3, b2) + b2 - B3 + b1*C1) * idet3;

        // conditioning check: fall back to pivoted GE on degenerate lanes
        double scale3 = fabs(a1)*fabs(CE1) + fabs(a2) + fabs(d3) + 2.0;
        bool good = isfinite(dl0) && isfinite(dl1) && isfinite(dl2) && isfinite(dl3)
                 && (fabs(a0)   > 1e-10 * (1.0 + fabs(D0)))
                 && (fabs(det3) > 1e-10 * scale3);

        if (!good) {
            // full pivoted 4x4 GE (round-6 path, value-tracks LAPACK)
            double P0[5] = { a0, 0.0, 0.0, 0.0, b0 };
            double P3[5] = { mu, -1.0, -1.0, d3, b3 };
            {
                bool sw = fabs(P3[0]) > fabs(P0[0]);
                #pragma unroll
                for (int c = 0; c < 5; ++c) { double a=P0[c], b=P3[c]; P0[c]=sw?b:a; P3[c]=sw?a:b; }
            }
            double ip0 = fast_rcp(P0[0]);
            {
                double f = P3[0] * ip0;
                #pragma unroll
                for (int c = 1; c < 5; ++c) P3[c] = fma(-f, P0[c], P3[c]);
            }
            double R1[4] = { a1, -1.0, 1.0, b1 };
            double R2[4] = { -1.0, a2, 1.0, b2 };
            double R3[4] = { P3[1], P3[2], P3[3], P3[4] };
            {
                bool sw = fabs(R2[0]) > fabs(R1[0]);
                #pragma unroll
                for (int c = 0; c < 4; ++c) { double a=R1[c], b=R2[c]; R1[c]=sw?b:a; R2[c]=sw?a:b; }
            }
            {
                bool sw = fabs(R3[0]) > fabs(R1[0]);
                #pragma unroll
                for (int c = 0; c < 4; ++c) { double a=R1[c], b=R3[c]; R1[c]=sw?b:a; R3[c]=sw?a:b; }
            }
            double ip1 = fast_rcp(R1[0]);
            {
                double f2 = R2[0] * ip1;
                double f3 = R3[0] * ip1;
                #pragma unroll
                for (int c = 1; c < 4; ++c) {
                    R2[c] = fma(-f2, R1[c], R2[c]);
                    R3[c] = fma(-f3, R1[c], R3[c]);
                }
            }
            {
                bool sw = fabs(R3[1]) > fabs(R2[1]);
                #pragma unroll
                for (int c = 1; c < 4; ++c) { double a=R2[c], b=R3[c]; R2[c]=sw?b:a; R3[c]=sw?a:b; }
            }
            double ip2 = fast_rcp(R2[1]);
            {
                double f = R3[1] * ip2;
                R3[2] = fma(-f, R2[2], R3[2]);
                R3[3] = fma(-f, R2[3], R3[3]);
            }
            double ip3 = fast_rcp(R3[2]);
            dl3 = R3[3] * ip3;
            dl2 = (R2[3] - R2[2]*dl3) * ip2;
            dl1 = (R1[3] - R1[1]*dl2 - R1[2]*dl3) * ip1;
            dl0 = (P0[4] - P0[1]*dl1 - P0[2]*dl2 - P0[3]*dl3) * ip0;
        }

        // eliminated-row back-substitution
        double dz0 = -rd0 - dl1 + dl2;
        double dz1 = -rd1 + dl0;

        double ds0 = -rp0 + dz1;
        double ds1 = -rp1 - dz0 + dl3;
        double ds2 = -rp2 + dz0 + dl3;
        double ds3 = -rp3 + (mu * dl0 - dl1 - dl2);

        // fraction-to-boundary: fp64 branch condition, fp32 ratio
        float amin = 3.0e12f;
        amin = fminf(amin, (dl0 < -1e-12) ? ((float)lam[0] * fast_rcpf((float)(-dl0))) : 3.0e12f);
        amin = fminf(amin, (dl1 < -1e-12) ? ((float)lam[1] * fast_rcpf((float)(-dl1))) : 3.0e12f);
        amin = fminf(amin, (dl2 < -1e-12) ? ((float)lam[2] * fast_rcpf((float)(-dl2))) : 3.0e12f);
        amin = fminf(amin, (dl3 < -1e-12) ? ((float)lam[3] * fast_rcpf((float)(-dl3))) : 3.0e12f);
        amin = fminf(amin, (ds0 < -1e-12) ? ((float)s[0] * fast_rcpf((float)(-ds0))) : 3.0e12f);
        amin = fminf(amin, (ds1 < -1e-12) ? ((float)s[1] * fast_rcpf((float)(-ds1))) : 3.0e12f);
        amin = fminf(amin, (ds2 < -1e-12) ? ((float)s[2] * fast_rcpf((float)(-ds2))) : 3.0e12f);
        amin = fminf(amin, (ds3 < -1e-12) ? ((float)s[3] * fast_rcpf((float)(-ds3))) : 3.0e12f);
        double alpha = fmin(1.0, 0.99 * (double)amin);

        z0 += alpha * dz0;
        z1 += alpha * dz1;
        lam[0] += alpha * dl0; lam[1] += alpha * dl1;
        lam[2] += alpha * dl2; lam[3] += alpha * dl3;
        s[0] += alpha * ds0; s[1] += alpha * ds1;
        s[2] += alpha * ds2; s[3] += alpha * ds3;

        // wave-uniform early exit: all lanes' step below 1e-11
        if (it >= 8) {
            float af = (float)alpha;
            float m1 = fmaxf(fabsf((float)dz0), fabsf((float)dz1));
            float m2 = fmaxf(fabsf((float)dl0), fabsf((float)dl1));
            float m3 = fmaxf(fabsf((float)dl2), fabsf((float)dl3));
            float m4 = fmaxf(fabsf((float)ds0), fabsf((float)ds1));
            float m5 = fmaxf(fabsf((float)ds2), fabsf((float)ds3));
            float stepm = af * fmaxf(fmaxf(m1, m2), fmaxf(m3, fmaxf(m4, m5)));
            if (__all(stepm < 1e-11f)) break;
        }
    }

    ((float2*)out)[i] = make_float2((float)z0, (float)z1);
}

extern "C" void kernel_launch(void* const* d_in, const int* in_sizes, int n_in,
                              void* d_out, int out_size, void* d_ws, size_t ws_size,
                              hipStream_t stream) {
    const float* pv = (const float*)d_in[0];
    const float* mu = (const float*)d_in[1];
    float* out = (float*)d_out;
    int n = in_sizes[0] / 2;  // B = 131072
    int block = 256;
    int grid = (n + block - 1) / block;
    lcp_kernel<<<grid, block, 0, stream>>>(pv, mu, out, n);
}